// Round 3
// baseline (1446.250 us; speedup 1.0000x reference)
//
#include <hip/hip_runtime.h>
#include <hip/hip_bf16.h>

#define NH 16
#define DM 1024
#define DK 64
#define SEQ 2048
#define NB 2

typedef __attribute__((ext_vector_type(8))) short short8;
typedef __attribute__((ext_vector_type(4))) float f32x4;
typedef __attribute__((ext_vector_type(4))) unsigned short us4;

__device__ __forceinline__ unsigned short f2bf(float f) {
    union { float f; unsigned int i; } v; v.f = f;
    unsigned int x = v.i;
    return (unsigned short)((x + 0x7fffu + ((x >> 16) & 1u)) >> 16);
}

// ---------------------------------------------------------------------------
// f32 -> bf16 conversion, 4 elems/thread. n must be a multiple of 4.
// ---------------------------------------------------------------------------
__global__ __launch_bounds__(256)
void cvt_f32_bf16(const float* __restrict__ src,
                  unsigned short* __restrict__ dst, int n)
{
    int i = (blockIdx.x * 256 + threadIdx.x) * 4;
    if (i >= n) return;
    float4 v = *(const float4*)(src + i);
    us4 o;
    o.x = f2bf(v.x); o.y = f2bf(v.y); o.z = f2bf(v.z); o.w = f2bf(v.w);
    *(us4*)(dst + i) = o;
}

// ---------------------------------------------------------------------------
// Y = A (bf16, M x K row-major) @ W(bf16, N x K row-major)^T, M=4096, K=N=1024
// mode 0: dst bf16, layout [b,h,s,d]   (Q / K projections)
// mode 1: dst bf16, layout [b,h,d,s]   (V projection, transposed for PV mfma)
// mode 3: dst bf16, plain row-major [M x N]  (fc projection)
// grid: 1024 blocks (64 mblk x 16 nblk), 256 threads (4 waves, each 16x64)
// ---------------------------------------------------------------------------
__global__ __launch_bounds__(256)
void gemm_xwT(const unsigned short* __restrict__ A,
              const unsigned short* __restrict__ W,
              unsigned short* __restrict__ dst, int mode)
{
    const int K = 1024;
    int bid  = blockIdx.x;
    int nblk = bid & 15, mblk = bid >> 4;
    int wave = threadIdx.x >> 6, lane = threadIdx.x & 63;
    int quad = lane >> 4, l16 = lane & 15;
    int m0 = mblk * 64 + wave * 16;
    int n0 = nblk * 64;

    f32x4 z = {0.f, 0.f, 0.f, 0.f};
    f32x4 acc[4] = {z, z, z, z};

    const unsigned short* arow = A + (size_t)(m0 + l16) * K + quad * 8;
    const unsigned short* wrow = W + (size_t)(n0 + l16) * K + quad * 8;

    for (int k0 = 0; k0 < K; k0 += 32) {
        short8 a = *(const short8*)(arow + k0);
#pragma unroll
        for (int j = 0; j < 4; ++j) {
            short8 b = *(const short8*)(wrow + (size_t)j * 16 * K + k0);
            acc[j] = __builtin_amdgcn_mfma_f32_16x16x32_bf16(a, b, acc[j], 0, 0, 0);
        }
    }

#pragma unroll
    for (int j = 0; j < 4; ++j)
#pragma unroll
        for (int r = 0; r < 4; ++r) {
            int m = m0 + quad * 4 + r;      // C row  (A index)
            int n = n0 + j * 16 + l16;      // C col  (B index)
            size_t off;
            if (mode == 3) {
                off = (size_t)m * DM + n;
            } else {
                int b = m >> 11, s = m & (SEQ - 1);
                int h = n >> 6,  d = n & (DK - 1);
                if (mode == 0)  off = (((size_t)(b * NH + h)) * SEQ + s) * DK + d;
                else            off = (((size_t)(b * NH + h)) * DK + d) * SEQ + s;
            }
            dst[off] = f2bf(acc[j][r]);
        }
}

// ---------------------------------------------------------------------------
// scores + mask + softmax -> writes normalized attn (f32) to d_out.
// grid: B*H*(S/64) = 1024 blocks; 4 waves, each owns 16 q-rows.
// 3 streaming passes over 128 k-tiles: row-max, sum-exp, normalized write.
// ---------------------------------------------------------------------------
__device__ __forceinline__ f32x4 score_tile(short8 a0, short8 a1,
                                            const unsigned short* kbase,
                                            int kt, int l16)
{
    const unsigned short* kp = kbase + (size_t)(kt * 16 + l16) * DK;
    short8 b0 = *(const short8*)(kp);
    short8 b1 = *(const short8*)(kp + 32);
    f32x4 acc = {0.f, 0.f, 0.f, 0.f};
    acc = __builtin_amdgcn_mfma_f32_16x16x32_bf16(a0, b0, acc, 0, 0, 0);
    acc = __builtin_amdgcn_mfma_f32_16x16x32_bf16(a1, b1, acc, 0, 0, 0);
    return acc;
}

__global__ __launch_bounds__(256)
void attn_scores(const unsigned short* __restrict__ Qb,
                 const unsigned short* __restrict__ Kb,
                 const int* __restrict__ mask,
                 float* __restrict__ attn)
{
    int bid  = blockIdx.x;
    int qblk = bid & 31;       // S/64 = 32
    int bh   = bid >> 5;       // 0..31
    int b    = bh >> 4;
    int wave = threadIdx.x >> 6, lane = threadIdx.x & 63;
    int quad = lane >> 4, l16 = lane & 15;
    int q0   = qblk * 64 + wave * 16;

    const unsigned short* qp = Qb + ((size_t)bh * SEQ + q0 + l16) * DK + quad * 8;
    short8 a0 = *(const short8*)(qp);
    short8 a1 = *(const short8*)(qp + 32);
    const unsigned short* kbase = Kb + (size_t)bh * SEQ * DK + quad * 8;
    const int* mbase = mask + ((size_t)(b * SEQ + q0 + quad * 4)) * SEQ + l16;

    // pass 1: row max
    float mr[4] = {-3e38f, -3e38f, -3e38f, -3e38f};
    for (int kt = 0; kt < 128; ++kt) {
        f32x4 acc = score_tile(a0, a1, kbase, kt, l16);
#pragma unroll
        for (int r = 0; r < 4; ++r) {
            float s = acc[r] * 0.125f;
            if (mbase[(size_t)r * SEQ + kt * 16]) s = -1e9f;
            mr[r] = fmaxf(mr[r], s);
        }
    }
#pragma unroll
    for (int r = 0; r < 4; ++r)
#pragma unroll
        for (int o = 1; o < 16; o <<= 1)
            mr[r] = fmaxf(mr[r], __shfl_xor(mr[r], o));

    // pass 2: sum of exp
    float lr[4] = {0.f, 0.f, 0.f, 0.f};
    for (int kt = 0; kt < 128; ++kt) {
        f32x4 acc = score_tile(a0, a1, kbase, kt, l16);
#pragma unroll
        for (int r = 0; r < 4; ++r) {
            float s = acc[r] * 0.125f;
            if (mbase[(size_t)r * SEQ + kt * 16]) s = -1e9f;
            lr[r] += __expf(s - mr[r]);
        }
    }
#pragma unroll
    for (int r = 0; r < 4; ++r) {
#pragma unroll
        for (int o = 1; o < 16; o <<= 1)
            lr[r] += __shfl_xor(lr[r], o);
        lr[r] = 1.f / lr[r];
    }

    // pass 3: write normalized attn (f32)
    for (int kt = 0; kt < 128; ++kt) {
        f32x4 acc = score_tile(a0, a1, kbase, kt, l16);
#pragma unroll
        for (int r = 0; r < 4; ++r) {
            float s = acc[r] * 0.125f;
            if (mbase[(size_t)r * SEQ + kt * 16]) s = -1e9f;
            float e = __expf(s - mr[r]) * lr[r];
            attn[((size_t)bh * SEQ + q0 + quad * 4 + r) * SEQ + kt * 16 + l16] = e;
        }
    }
}

// ---------------------------------------------------------------------------
// context = attn(f32) @ V  -> ctx bf16 [B*S, DM] row-major (col = h*64 + dv)
// grid: B*H*(S/64) = 1024 blocks; 4 waves each 16q x 64dv, K=2048.
// ---------------------------------------------------------------------------
__global__ __launch_bounds__(256)
void attn_ctx(const float* __restrict__ attn,
              const unsigned short* __restrict__ Vt,
              unsigned short* __restrict__ ctx)
{
    int bid  = blockIdx.x;
    int mblk = bid & 31;
    int bh   = bid >> 5;
    int wave = threadIdx.x >> 6, lane = threadIdx.x & 63;
    int quad = lane >> 4, l16 = lane & 15;
    int q0   = mblk * 64 + wave * 16;

    const float* ap = attn + ((size_t)bh * SEQ + q0 + l16) * SEQ + quad * 8;
    const unsigned short* vbase = Vt + (size_t)bh * DK * SEQ + quad * 8;

    f32x4 z = {0.f, 0.f, 0.f, 0.f};
    f32x4 acc[4] = {z, z, z, z};

    for (int kt = 0; kt < 64; ++kt) {
        float4 a0 = *(const float4*)(ap + kt * 32);
        float4 a1 = *(const float4*)(ap + kt * 32 + 4);
        short8 a;
        a[0] = (short)f2bf(a0.x); a[1] = (short)f2bf(a0.y);
        a[2] = (short)f2bf(a0.z); a[3] = (short)f2bf(a0.w);
        a[4] = (short)f2bf(a1.x); a[5] = (short)f2bf(a1.y);
        a[6] = (short)f2bf(a1.z); a[7] = (short)f2bf(a1.w);
#pragma unroll
        for (int j = 0; j < 4; ++j) {
            short8 bfr = *(const short8*)(vbase + (size_t)(j * 16 + l16) * SEQ + kt * 32);
            acc[j] = __builtin_amdgcn_mfma_f32_16x16x32_bf16(a, bfr, acc[j], 0, 0, 0);
        }
    }

    int b = bh >> 4, h = bh & 15;
#pragma unroll
    for (int j = 0; j < 4; ++j)
#pragma unroll
        for (int r = 0; r < 4; ++r) {
            int q = q0 + quad * 4 + r;
            ctx[((size_t)b * SEQ + q) * DM + h * DK + j * 16 + l16] = f2bf(acc[j][r]);
        }
}

// ---------------------------------------------------------------------------
// out = LayerNorm(y + input_Q), gamma=1 beta=0; one block per row.
// y bf16, inQ f32, out f32.
// ---------------------------------------------------------------------------
__global__ __launch_bounds__(256)
void ln_resid(const unsigned short* __restrict__ y,
              const float* __restrict__ inq,
              float* __restrict__ out)
{
    int row = blockIdx.x, t = threadIdx.x;
    const unsigned short* yr = y + (size_t)row * DM;
    const float* qr = inq + (size_t)row * DM;

    float4 qv = *(const float4*)(qr + t * 4);
    us4 yv = *(const us4*)(yr + t * 4);
    float x[4];
    {
        union { unsigned int i; float f; } c;
        c.i = ((unsigned int)yv.x) << 16; x[0] = c.f + qv.x;
        c.i = ((unsigned int)yv.y) << 16; x[1] = c.f + qv.y;
        c.i = ((unsigned int)yv.z) << 16; x[2] = c.f + qv.z;
        c.i = ((unsigned int)yv.w) << 16; x[3] = c.f + qv.w;
    }

    float s1 = x[0] + x[1] + x[2] + x[3];
    float s2 = x[0]*x[0] + x[1]*x[1] + x[2]*x[2] + x[3]*x[3];
#pragma unroll
    for (int o = 32; o; o >>= 1) {
        s1 += __shfl_xor(s1, o);
        s2 += __shfl_xor(s2, o);
    }
    __shared__ float r1[4], r2[4];
    int wave = t >> 6, lane = t & 63;
    if (lane == 0) { r1[wave] = s1; r2[wave] = s2; }
    __syncthreads();
    float t1 = r1[0] + r1[1] + r1[2] + r1[3];
    float t2 = r2[0] + r2[1] + r2[2] + r2[3];
    float mu  = t1 * (1.f / DM);
    float var = t2 * (1.f / DM) - mu * mu;
    float rs  = rsqrtf(var + 1e-5f);

    float4 o4;
    o4.x = (x[0] - mu) * rs;
    o4.y = (x[1] - mu) * rs;
    o4.z = (x[2] - mu) * rs;
    o4.w = (x[3] - mu) * rs;
    *(float4*)(out + (size_t)row * DM + t * 4) = o4;
}

// ---------------------------------------------------------------------------
// All I/O is f32. Internal pipeline bf16 (MFMA). Workspace plan, peak 26 MB:
//   A = ws+0   (8 MB)   B = ws+8M (8 MB)   C = ws+16M (8 MB)   Wb = ws+24M (2 MB)
//   cvt inQ->C, WQ->Wb;  Qb = gemm(C,Wb) -> A        (mode 0)
//   cvt inK->C, WK->Wb;  Kb = gemm(C,Wb) -> B        (mode 0)
//   attn_scores(A,B,mask) -> d_out.attn (f32)
//   cvt inV->C, WV->Wb;  Vt = gemm(C,Wb) -> A        (mode 1, Q dead)
//   attn_ctx(d_out.attn, A) -> B                      (K dead)
//   cvt Wfc->Wb;         y  = gemm(B,Wb) -> C        (mode 3, inV copy dead)
//   ln_resid(C, inQ) -> d_out.out (f32)
// ---------------------------------------------------------------------------
extern "C" void kernel_launch(void* const* d_in, const int* in_sizes, int n_in,
                              void* d_out, int out_size, void* d_ws, size_t ws_size,
                              hipStream_t stream)
{
    const float* inQ = (const float*)d_in[0];
    const float* inK = (const float*)d_in[1];
    const float* inV = (const float*)d_in[2];
    const int*   msk = (const int*)d_in[3];
    const float* WQ  = (const float*)d_in[4];
    const float* WK  = (const float*)d_in[5];
    const float* WV  = (const float*)d_in[6];
    const float* Wfc = (const float*)d_in[7];

    float* out  = (float*)d_out;
    float* attn = out + (size_t)NB * SEQ * DM;   // 4,194,304 floats offset

    char* ws = (char*)d_ws;
    unsigned short* regA = (unsigned short*)(ws);
    unsigned short* regB = (unsigned short*)(ws + ((size_t)8  << 20));
    unsigned short* regC = (unsigned short*)(ws + ((size_t)16 << 20));
    unsigned short* Wb   = (unsigned short*)(ws + ((size_t)24 << 20));

    const int NIN = NB * SEQ * DM;   // 4M elems
    const int NW  = DM * DM;         // 1M elems

    cvt_f32_bf16<<<NIN / 1024, 256, 0, stream>>>(inQ, regC, NIN);
    cvt_f32_bf16<<<NW  / 1024, 256, 0, stream>>>(WQ, Wb, NW);
    gemm_xwT<<<1024, 256, 0, stream>>>(regC, Wb, regA, 0);   // Qb -> A

    cvt_f32_bf16<<<NIN / 1024, 256, 0, stream>>>(inK, regC, NIN);
    cvt_f32_bf16<<<NW  / 1024, 256, 0, stream>>>(WK, Wb, NW);
    gemm_xwT<<<1024, 256, 0, stream>>>(regC, Wb, regB, 0);   // Kb -> B

    attn_scores<<<1024, 256, 0, stream>>>(regA, regB, msk, attn);

    cvt_f32_bf16<<<NIN / 1024, 256, 0, stream>>>(inV, regC, NIN);
    cvt_f32_bf16<<<NW  / 1024, 256, 0, stream>>>(WV, Wb, NW);
    gemm_xwT<<<1024, 256, 0, stream>>>(regC, Wb, regA, 1);   // Vt -> A

    attn_ctx<<<1024, 256, 0, stream>>>(attn, regA, regB);    // ctx -> B

    cvt_f32_bf16<<<NW / 1024, 256, 0, stream>>>(Wfc, Wb, NW);
    gemm_xwT<<<1024, 256, 0, stream>>>(regB, Wb, regC, 3);   // y -> C

    ln_resid<<<4096, 256, 0, stream>>>(regC, inQ, out);
}